// Round 9
// baseline (240.338 us; speedup 1.0000x reference)
//
#include <hip/hip_runtime.h>
#include <hip/hip_bf16.h>

// LinearStitcher, round 9: r8 + LDS-transposed epilogue (all stores dwordx4).
// x: [16384, 4096] f32, W: [16,128,256] f32, b: [16,128] f32.
// out[:, a*128+c] = sum_k x[:, a*256+k]*W[a,c,k] + b[a,c];  out[:, 2048:] = 0.
//
// The MFMA C/D layout forces 4B scalar result stores (16/thread). This round
// routes the result through a padded LDS tile ([32][132] f32, pitch-132 makes
// both phases bank-optimal) so the whole write stream becomes nt dwordx4 —
// same packing as the 7 TB/s fill kernel.

typedef __attribute__((ext_vector_type(8))) short bf16x8;
typedef __attribute__((ext_vector_type(16))) float f32x16;
typedef __attribute__((ext_vector_type(4)))  float f32x4;

static constexpr int NX   = 4096;
static constexpr int OW   = 4096;
static constexpr int KDIM = 256;
static constexpr int CCH  = 128;

// P[a][ks(16)][n(4)][lane(64)] : 16B slot, exact 32x32x16 B-fragment layout
__global__ __launch_bounds__(256)
void prep_w(const float* __restrict__ W, __hip_bfloat16* __restrict__ P) {
    const int s = blockIdx.x * 256 + threadIdx.x;     // 256 blocks, 1 slot/thread
    const int a  = s >> 12;
    const int w  = s & 4095;
    const int ks = w >> 8;
    const int n  = (w >> 6) & 3;
    const int l  = w & 63;
    const int ch = n * 32 + (l & 31);
    const int k0 = ks * 16 + (l >> 5) * 8;
    const float* src = W + ((long)a * CCH + ch) * KDIM + k0;
    const f32x4 w0 = *(const f32x4*)(src);
    const f32x4 w1 = *(const f32x4*)(src + 4);
    union { bf16x8 v; __hip_bfloat162 h[4]; } pw;
    pw.h[0] = __float22bfloat162_rn(make_float2(w0.x, w0.y));
    pw.h[1] = __float22bfloat162_rn(make_float2(w0.z, w0.w));
    pw.h[2] = __float22bfloat162_rn(make_float2(w1.x, w1.y));
    pw.h[3] = __float22bfloat162_rn(make_float2(w1.z, w1.w));
    *(bf16x8*)((char*)P + ((long)s << 4)) = pw.v;
}

__global__ __launch_bounds__(256, 8)
void stitch_kernel(const float* __restrict__ x,
                   const __hip_bfloat16* __restrict__ Pw,
                   const float* __restrict__ bias,
                   float* __restrict__ out) {
    const int tid  = threadIdx.x;
    const int lane = tid & 63;
    const int wid  = tid >> 6;
    const int bid  = blockIdx.x;
    const int area = bid & 15;                 // same-area blocks -> same XCD
    const int rowbase = (bid >> 4) * 32;

    // staging (bf16, first 16384 B) and epilogue tile ([32][132] f32) alias.
    __shared__ char As[32 * 132 * 4];          // 16896 B -> 8 blocks/CU

    const float* xb = x + (long)rowbase * NX + area * KDIM + (lane << 2);
    const int slotl   = lane >> 1;
    const int halfoff = (lane & 1) << 3;

    // batch 0: rows wid + 4i (i=0..3), nt loads (pure streaming)
    f32x4 sv[4];
#pragma unroll
    for (int i = 0; i < 4; ++i)
        sv[i] = __builtin_nontemporal_load(
            (const f32x4*)(xb + (long)(wid + (i << 2)) * NX));

    // zero mirror half (nt dwordx4): rows rowbase..+32, cols 2048+area*128..+128
    {
        f32x4* o4 = (f32x4*)out + 512 + area * (CCH / 4);
        const f32x4 z = {0.f, 0.f, 0.f, 0.f};
#pragma unroll
        for (int i = 0; i < 4; ++i) {
            const int idx = i * 256 + tid;     // 32 rows x 32 f32x4
            const int r = idx >> 5, g = idx & 31;
            __builtin_nontemporal_store(z, o4 + (long)(rowbase + r) * (OW / 4) + g);
        }
    }

#pragma unroll
    for (int i = 0; i < 4; ++i) {
        const int r = wid + (i << 2);
        union { unsigned long long u; __hip_bfloat162 h[2]; } pw;
        pw.h[0] = __float22bfloat162_rn(make_float2(sv[i].x, sv[i].y));
        pw.h[1] = __float22bfloat162_rn(make_float2(sv[i].z, sv[i].w));
        *(unsigned long long*)(&As[(r << 9) + ((slotl ^ (r & 7)) << 4) + halfoff]) = pw.u;
    }

    // batch 1: rows wid + 16 + 4i
#pragma unroll
    for (int i = 0; i < 4; ++i)
        sv[i] = __builtin_nontemporal_load(
            (const f32x4*)(xb + (long)(wid + 16 + (i << 2)) * NX));
#pragma unroll
    for (int i = 0; i < 4; ++i) {
        const int r = wid + 16 + (i << 2);
        union { unsigned long long u; __hip_bfloat162 h[2]; } pw;
        pw.h[0] = __float22bfloat162_rn(make_float2(sv[i].x, sv[i].y));
        pw.h[1] = __float22bfloat162_rn(make_float2(sv[i].z, sv[i].w));
        *(unsigned long long*)(&As[(r << 9) + ((slotl ^ (r & 7)) << 4) + halfoff]) = pw.u;
    }
    __syncthreads();

    // K-loop: wave `wid` computes the 32x32 quadrant n=wid of this area.
    const int row = lane & 31;                 // col within quadrant
    const int kh  = lane >> 5;
    const bf16x8* bpa = (const bf16x8*)Pw + (long)area * 4096 + wid * 64 + lane;

    f32x16 acc;
#pragma unroll
    for (int r = 0; r < 16; ++r) acc[r] = 0.f;

#pragma unroll
    for (int ks = 0; ks < 16; ++ks) {
        const int slot = (ks << 1) + kh;
        const bf16x8 af = *(const bf16x8*)(&As[(row << 9) + ((slot ^ (row & 7)) << 4)]);
        const bf16x8 bf = bpa[ks << 8];        // cached: W-pack stays L2-hot
        acc = __builtin_amdgcn_mfma_f32_32x32x16_bf16(af, bf, acc, 0, 0, 0);
    }

    // epilogue via LDS transpose: scalar LDS writes (bank-clean), then each
    // thread stores 64B contiguous with nt dwordx4.
    __syncthreads();                           // all waves done reading As
    {
        float* Ts = (float*)As;                // [32][132] f32
        const int c = wid * 32 + row;          // col within 128
        const float bv = bias[area * CCH + c];
#pragma unroll
        for (int r = 0; r < 16; ++r) {
            const int orow = (r & 3) + ((r >> 2) << 3) + (kh << 2);
            Ts[orow * 132 + c] = acc[r] + bv;
        }
    }
    __syncthreads();
    {
        const float* Ts = (const float*)As;
        const int tr = tid >> 3;               // 0..31
        const int tc = (tid & 7) << 4;         // 0..112
        const float* srcr = Ts + tr * 132 + tc;
        float* dst = out + (long)(rowbase + tr) * OW + area * CCH + tc;
#pragma unroll
        for (int j = 0; j < 4; ++j) {
            const f32x4 v = *(const f32x4*)(srcr + (j << 2));
            __builtin_nontemporal_store(v, (f32x4*)(dst + (j << 2)));
        }
    }
}

extern "C" void kernel_launch(void* const* d_in, const int* in_sizes, int n_in,
                              void* d_out, int out_size, void* d_ws, size_t ws_size,
                              hipStream_t stream) {
    const float* x    = (const float*)d_in[0];
    const float* W    = (const float*)d_in[1];
    const float* bias = (const float*)d_in[2];
    float* out = (float*)d_out;
    __hip_bfloat16* P = (__hip_bfloat16*)d_ws;   // 1 MB packed W fragments

    prep_w<<<256, 256, 0, stream>>>(W, P);
    stitch_kernel<<<8192, 256, 0, stream>>>(x, P, bias, out);
}

// Round 10
// 98.212 us; speedup vs baseline: 2.4471x; 2.4471x over previous
//
#include <hip/hip_runtime.h>
#include <hip/hip_bf16.h>

// LinearStitcher, round 10: r8 structure (110us, best), single change:
// x loads are TEMPORAL (plain) to encourage L3 residency across replays;
// out stores remain nontemporal (pure write streams).
// x: [16384, 4096] f32, W: [16,128,256] f32, b: [16,128] f32.
// out[:, a*128+c] = sum_k x[:, a*256+k]*W[a,c,k] + b[a,c];  out[:, 2048:] = 0.

typedef __attribute__((ext_vector_type(8))) short bf16x8;
typedef __attribute__((ext_vector_type(16))) float f32x16;
typedef __attribute__((ext_vector_type(4)))  float f32x4;

static constexpr int NX   = 4096;
static constexpr int OW   = 4096;
static constexpr int KDIM = 256;
static constexpr int CCH  = 128;

// P[a][ks(16)][n(4)][lane(64)] : 16B slot, exact 32x32x16 B-fragment layout
__global__ __launch_bounds__(256)
void prep_w(const float* __restrict__ W, __hip_bfloat16* __restrict__ P) {
    const int s = blockIdx.x * 256 + threadIdx.x;     // 256 blocks, 1 slot/thread
    const int a  = s >> 12;
    const int w  = s & 4095;
    const int ks = w >> 8;
    const int n  = (w >> 6) & 3;
    const int l  = w & 63;
    const int ch = n * 32 + (l & 31);
    const int k0 = ks * 16 + (l >> 5) * 8;
    const float* src = W + ((long)a * CCH + ch) * KDIM + k0;
    const f32x4 w0 = *(const f32x4*)(src);
    const f32x4 w1 = *(const f32x4*)(src + 4);
    union { bf16x8 v; __hip_bfloat162 h[4]; } pw;
    pw.h[0] = __float22bfloat162_rn(make_float2(w0.x, w0.y));
    pw.h[1] = __float22bfloat162_rn(make_float2(w0.z, w0.w));
    pw.h[2] = __float22bfloat162_rn(make_float2(w1.x, w1.y));
    pw.h[3] = __float22bfloat162_rn(make_float2(w1.z, w1.w));
    *(bf16x8*)((char*)P + ((long)s << 4)) = pw.v;
}

__global__ __launch_bounds__(256, 8)
void stitch_kernel(const float* __restrict__ x,
                   const __hip_bfloat16* __restrict__ Pw,
                   const float* __restrict__ bias,
                   float* __restrict__ out) {
    const int tid  = threadIdx.x;
    const int lane = tid & 63;
    const int wid  = tid >> 6;
    const int bid  = blockIdx.x;
    const int area = bid & 15;                 // same-area blocks -> same XCD
    const int rowbase = (bid >> 4) * 32;

    __shared__ char As[32 * 512];              // [32 rows][256 k] bf16, 16 KB

    const float* xb = x + (long)rowbase * NX + area * KDIM + (lane << 2);
    const int slotl   = lane >> 1;
    const int halfoff = (lane & 1) << 3;

    // batch 0: rows wid + 4i (i=0..3), TEMPORAL loads (let x live in L3)
    f32x4 sv[4];
#pragma unroll
    for (int i = 0; i < 4; ++i)
        sv[i] = *(const f32x4*)(xb + (long)(wid + (i << 2)) * NX);

    // zero mirror half (nt stores, overlap load latency):
    // rows rowbase..+32, cols 2048+area*128..+128
    {
        f32x4* o4 = (f32x4*)out + 512 + area * (CCH / 4);
        const f32x4 z = {0.f, 0.f, 0.f, 0.f};
#pragma unroll
        for (int i = 0; i < 4; ++i) {
            const int idx = i * 256 + tid;     // 32 rows x 32 f32x4
            const int r = idx >> 5, g = idx & 31;
            __builtin_nontemporal_store(z, o4 + (long)(rowbase + r) * (OW / 4) + g);
        }
    }

#pragma unroll
    for (int i = 0; i < 4; ++i) {
        const int r = wid + (i << 2);
        union { unsigned long long u; __hip_bfloat162 h[2]; } pw;
        pw.h[0] = __float22bfloat162_rn(make_float2(sv[i].x, sv[i].y));
        pw.h[1] = __float22bfloat162_rn(make_float2(sv[i].z, sv[i].w));
        *(unsigned long long*)(&As[(r << 9) + ((slotl ^ (r & 7)) << 4) + halfoff]) = pw.u;
    }

    // batch 1: rows wid + 16 + 4i
#pragma unroll
    for (int i = 0; i < 4; ++i)
        sv[i] = *(const f32x4*)(xb + (long)(wid + 16 + (i << 2)) * NX);
#pragma unroll
    for (int i = 0; i < 4; ++i) {
        const int r = wid + 16 + (i << 2);
        union { unsigned long long u; __hip_bfloat162 h[2]; } pw;
        pw.h[0] = __float22bfloat162_rn(make_float2(sv[i].x, sv[i].y));
        pw.h[1] = __float22bfloat162_rn(make_float2(sv[i].z, sv[i].w));
        *(unsigned long long*)(&As[(r << 9) + ((slotl ^ (r & 7)) << 4) + halfoff]) = pw.u;
    }
    __syncthreads();

    // K-loop: wave `wid` computes the 32x32 quadrant n=wid of this area.
    const int row = lane & 31;
    const int kh  = lane >> 5;
    const bf16x8* bpa = (const bf16x8*)Pw + (long)area * 4096 + wid * 64 + lane;

    f32x16 acc;
#pragma unroll
    for (int r = 0; r < 16; ++r) acc[r] = 0.f;

#pragma unroll
    for (int ks = 0; ks < 16; ++ks) {
        const int slot = (ks << 1) + kh;
        const bf16x8 af = *(const bf16x8*)(&As[(row << 9) + ((slot ^ (row & 7)) << 4)]);
        const bf16x8 bf = bpa[ks << 8];        // cached: W-pack stays L2-hot
        acc = __builtin_amdgcn_mfma_f32_32x32x16_bf16(af, bf, acc, 0, 0, 0);
    }

    // epilogue: C/D col = lane&31, row = (reg&3) + 8*(reg>>2) + 4*(lane>>5)
    const int gcol = area * CCH + wid * 32 + row;
    const float bv = bias[gcol];
    const long rb = rowbase + 4 * kh;
#pragma unroll
    for (int r = 0; r < 16; ++r) {
        const long grow = rb + (r & 3) + ((r >> 2) << 3);
        __builtin_nontemporal_store(acc[r] + bv, out + grow * OW + gcol);
    }
}

extern "C" void kernel_launch(void* const* d_in, const int* in_sizes, int n_in,
                              void* d_out, int out_size, void* d_ws, size_t ws_size,
                              hipStream_t stream) {
    const float* x    = (const float*)d_in[0];
    const float* W    = (const float*)d_in[1];
    const float* bias = (const float*)d_in[2];
    float* out = (float*)d_out;
    __hip_bfloat16* P = (__hip_bfloat16*)d_ws;   // 1 MB packed W fragments

    prep_w<<<256, 256, 0, stream>>>(W, P);
    stitch_kernel<<<8192, 256, 0, stream>>>(x, P, bias, out);
}

// Round 11
// 94.535 us; speedup vs baseline: 2.5423x; 1.0389x over previous
//
#include <hip/hip_runtime.h>
#include <hip/hip_bf16.h>

// LinearStitcher, round 11: r10 exactly, single knob: waves/EU 8 -> 6.
// Theory: at 64 VGPR/wave the K-loop's 16 independent L2 B-loads can't be
// hoisted (only ~2-4 in flight) -> each wave serializes on L2 latency.
// 85 VGPR/wave (occ 6) lets the compiler batch B-loads; TLP 32->24 waves/CU.
// x: [16384, 4096] f32, W: [16,128,256] f32, b: [16,128] f32.
// out[:, a*128+c] = sum_k x[:, a*256+k]*W[a,c,k] + b[a,c];  out[:, 2048:] = 0.

typedef __attribute__((ext_vector_type(8))) short bf16x8;
typedef __attribute__((ext_vector_type(16))) float f32x16;
typedef __attribute__((ext_vector_type(4)))  float f32x4;

static constexpr int NX   = 4096;
static constexpr int OW   = 4096;
static constexpr int KDIM = 256;
static constexpr int CCH  = 128;

// P[a][ks(16)][n(4)][lane(64)] : 16B slot, exact 32x32x16 B-fragment layout
__global__ __launch_bounds__(256)
void prep_w(const float* __restrict__ W, __hip_bfloat16* __restrict__ P) {
    const int s = blockIdx.x * 256 + threadIdx.x;     // 256 blocks, 1 slot/thread
    const int a  = s >> 12;
    const int w  = s & 4095;
    const int ks = w >> 8;
    const int n  = (w >> 6) & 3;
    const int l  = w & 63;
    const int ch = n * 32 + (l & 31);
    const int k0 = ks * 16 + (l >> 5) * 8;
    const float* src = W + ((long)a * CCH + ch) * KDIM + k0;
    const f32x4 w0 = *(const f32x4*)(src);
    const f32x4 w1 = *(const f32x4*)(src + 4);
    union { bf16x8 v; __hip_bfloat162 h[4]; } pw;
    pw.h[0] = __float22bfloat162_rn(make_float2(w0.x, w0.y));
    pw.h[1] = __float22bfloat162_rn(make_float2(w0.z, w0.w));
    pw.h[2] = __float22bfloat162_rn(make_float2(w1.x, w1.y));
    pw.h[3] = __float22bfloat162_rn(make_float2(w1.z, w1.w));
    *(bf16x8*)((char*)P + ((long)s << 4)) = pw.v;
}

__global__ __launch_bounds__(256, 6)
void stitch_kernel(const float* __restrict__ x,
                   const __hip_bfloat16* __restrict__ Pw,
                   const float* __restrict__ bias,
                   float* __restrict__ out) {
    const int tid  = threadIdx.x;
    const int lane = tid & 63;
    const int wid  = tid >> 6;
    const int bid  = blockIdx.x;
    const int area = bid & 15;                 // same-area blocks -> same XCD
    const int rowbase = (bid >> 4) * 32;

    __shared__ char As[32 * 512];              // [32 rows][256 k] bf16, 16 KB

    const float* xb = x + (long)rowbase * NX + area * KDIM + (lane << 2);
    const int slotl   = lane >> 1;
    const int halfoff = (lane & 1) << 3;

    // batch 0: rows wid + 4i (i=0..3), TEMPORAL loads (let x live in L3)
    f32x4 sv[4];
#pragma unroll
    for (int i = 0; i < 4; ++i)
        sv[i] = *(const f32x4*)(xb + (long)(wid + (i << 2)) * NX);

    // zero mirror half (nt stores, overlap load latency):
    // rows rowbase..+32, cols 2048+area*128..+128
    {
        f32x4* o4 = (f32x4*)out + 512 + area * (CCH / 4);
        const f32x4 z = {0.f, 0.f, 0.f, 0.f};
#pragma unroll
        for (int i = 0; i < 4; ++i) {
            const int idx = i * 256 + tid;     // 32 rows x 32 f32x4
            const int r = idx >> 5, g = idx & 31;
            __builtin_nontemporal_store(z, o4 + (long)(rowbase + r) * (OW / 4) + g);
        }
    }

#pragma unroll
    for (int i = 0; i < 4; ++i) {
        const int r = wid + (i << 2);
        union { unsigned long long u; __hip_bfloat162 h[2]; } pw;
        pw.h[0] = __float22bfloat162_rn(make_float2(sv[i].x, sv[i].y));
        pw.h[1] = __float22bfloat162_rn(make_float2(sv[i].z, sv[i].w));
        *(unsigned long long*)(&As[(r << 9) + ((slotl ^ (r & 7)) << 4) + halfoff]) = pw.u;
    }

    // batch 1: rows wid + 16 + 4i
#pragma unroll
    for (int i = 0; i < 4; ++i)
        sv[i] = *(const f32x4*)(xb + (long)(wid + 16 + (i << 2)) * NX);
#pragma unroll
    for (int i = 0; i < 4; ++i) {
        const int r = wid + 16 + (i << 2);
        union { unsigned long long u; __hip_bfloat162 h[2]; } pw;
        pw.h[0] = __float22bfloat162_rn(make_float2(sv[i].x, sv[i].y));
        pw.h[1] = __float22bfloat162_rn(make_float2(sv[i].z, sv[i].w));
        *(unsigned long long*)(&As[(r << 9) + ((slotl ^ (r & 7)) << 4) + halfoff]) = pw.u;
    }
    __syncthreads();

    // K-loop: wave `wid` computes the 32x32 quadrant n=wid of this area.
    const int row = lane & 31;
    const int kh  = lane >> 5;
    const bf16x8* bpa = (const bf16x8*)Pw + (long)area * 4096 + wid * 64 + lane;

    f32x16 acc;
#pragma unroll
    for (int r = 0; r < 16; ++r) acc[r] = 0.f;

#pragma unroll
    for (int ks = 0; ks < 16; ++ks) {
        const int slot = (ks << 1) + kh;
        const bf16x8 af = *(const bf16x8*)(&As[(row << 9) + ((slot ^ (row & 7)) << 4)]);
        const bf16x8 bf = bpa[ks << 8];        // cached: W-pack stays L2-hot
        acc = __builtin_amdgcn_mfma_f32_32x32x16_bf16(af, bf, acc, 0, 0, 0);
    }

    // epilogue: C/D col = lane&31, row = (reg&3) + 8*(reg>>2) + 4*(lane>>5)
    const int gcol = area * CCH + wid * 32 + row;
    const float bv = bias[gcol];
    const long rb = rowbase + 4 * kh;
#pragma unroll
    for (int r = 0; r < 16; ++r) {
        const long grow = rb + (r & 3) + ((r >> 2) << 3);
        __builtin_nontemporal_store(acc[r] + bv, out + grow * OW + gcol);
    }
}

extern "C" void kernel_launch(void* const* d_in, const int* in_sizes, int n_in,
                              void* d_out, int out_size, void* d_ws, size_t ws_size,
                              hipStream_t stream) {
    const float* x    = (const float*)d_in[0];
    const float* W    = (const float*)d_in[1];
    const float* bias = (const float*)d_in[2];
    float* out = (float*)d_out;
    __hip_bfloat16* P = (__hip_bfloat16*)d_ws;   // 1 MB packed W fragments

    prep_w<<<256, 256, 0, stream>>>(W, P);
    stitch_kernel<<<8192, 256, 0, stream>>>(x, P, bias, out);
}